// Round 15
// baseline (50.464 us; speedup 1.0000x reference)
//
#include <hip/hip_runtime.h>
#include <hip/hip_bf16.h>
#include <stdint.h>

#define DIM 1024
#define T_LEN 2048
#define NB 2
#define NH 16
#define HD 64
#define NQT 32   // 2048/64 q-tiles

typedef float f32x2 __attribute__((ext_vector_type(2)));
typedef float f32x4 __attribute__((ext_vector_type(4)));
typedef float f32x16 __attribute__((ext_vector_type(16)));
typedef __bf16 bf16x8 __attribute__((ext_vector_type(8)));
typedef __bf16 bf16x2 __attribute__((ext_vector_type(2)));
typedef unsigned int u32;
typedef unsigned int u32x4 __attribute__((ext_vector_type(4)));

template <int N> struct ICT { static constexpr int v = N; };

// ---- task table: tk = qt | lo<<6 | cnt<<12 | dst<<18 (dst 0=out,1=wsA,2=wsB)
#define TK(qt, lo, cnt, dst) ((u32)((qt) | ((lo) << 6) | ((cnt) << 12) | ((dst) << 18)))
// [0..47]  split schedule, LPT order (48 tasks/bh: 32 halves + 16 direct)
// [48..79] mono schedule (qt=31..0 heavy-first, all direct)
__constant__ u32 TASKS[80] = {
    TK(31,0,16,1), TK(31,16,16,2), TK(30,15,16,2), TK(15,0,16,0),
    TK(30,0,15,1), TK(29,0,15,1),  TK(29,15,15,2), TK(28,14,15,2), TK(14,0,15,0),
    TK(28,0,14,1), TK(27,0,14,1),  TK(27,14,14,2), TK(26,13,14,2), TK(13,0,14,0),
    TK(26,0,13,1), TK(25,0,13,1),  TK(25,13,13,2), TK(24,12,13,2), TK(12,0,13,0),
    TK(24,0,12,1), TK(23,0,12,1),  TK(23,12,12,2), TK(22,11,12,2), TK(11,0,12,0),
    TK(22,0,11,1), TK(21,0,11,1),  TK(21,11,11,2), TK(20,10,11,2), TK(10,0,11,0),
    TK(20,0,10,1), TK(19,0,10,1),  TK(19,10,10,2), TK(18,9,10,2),  TK(9,0,10,0),
    TK(18,0,9,1),  TK(17,0,9,1),   TK(17,9,9,2),   TK(16,8,9,2),   TK(8,0,9,0),
    TK(16,0,8,1),  TK(7,0,8,0),
    TK(6,0,7,0), TK(5,0,6,0), TK(4,0,5,0), TK(3,0,4,0),
    TK(2,0,3,0), TK(1,0,2,0), TK(0,0,1,0),
    // mono: qt = 31..0
    TK(31,0,32,0), TK(30,0,31,0), TK(29,0,30,0), TK(28,0,29,0),
    TK(27,0,28,0), TK(26,0,27,0), TK(25,0,26,0), TK(24,0,25,0),
    TK(23,0,24,0), TK(22,0,23,0), TK(21,0,22,0), TK(20,0,21,0),
    TK(19,0,20,0), TK(18,0,19,0), TK(17,0,18,0), TK(16,0,17,0),
    TK(15,0,16,0), TK(14,0,15,0), TK(13,0,14,0), TK(12,0,13,0),
    TK(11,0,12,0), TK(10,0,11,0), TK(9,0,10,0),  TK(8,0,9,0),
    TK(7,0,8,0),   TK(6,0,7,0),   TK(5,0,6,0),   TK(4,0,5,0),
    TK(3,0,4,0),   TK(2,0,3,0),   TK(1,0,2,0),   TK(0,0,1,0),
};
#define NSPLIT 48

__device__ __forceinline__ float sgnf(float v) {
    return (v > 0.f) ? 1.f : ((v < 0.f) ? -1.f : 0.f);
}

// async global -> LDS, 16B per lane; LDS dest is wave-uniform base + lane*16
__device__ __forceinline__ void gload16(const __bf16* g, __bf16* l) {
    __builtin_amdgcn_global_load_lds(
        (__attribute__((address_space(1))) void*)g,
        (__attribute__((address_space(3))) void*)l,
        16, 0, 0);
}

// ---------------- prepass: x(f32) -> Xb (bf16), Xq (bf16, QK-SIGN-GATED), Xt (bf16 [b][h][d][t], V-SIGN-GATED) ----------------
__global__ __launch_bounds__(256) void prep_kernel(
    const float* __restrict__ x, const float* __restrict__ bvq,
    const float* __restrict__ bvk, const float* __restrict__ bvv,
    __bf16* __restrict__ xb, __bf16* __restrict__ xq, __bf16* __restrict__ xt)
{
    __shared__ __align__(16) __bf16 tile[64][72];

    const int bid = blockIdx.x;
    const int h = bid & 15, tmp = bid >> 4, tt = tmp & 31, b = tmp >> 5;
    const int tid = threadIdx.x;
    const int r = tid >> 2, c0 = (tid & 3) * 16;

    const size_t rowbase = ((size_t)(b * T_LEN + tt * 64 + r)) * DIM + h * HD + c0;
    const float* xp = x + rowbase;

    float f[16];
    #pragma unroll
    for (int i = 0; i < 16; i += 4) {
        f32x4 v4 = *(const f32x4*)(xp + i);
        #pragma unroll
        for (int j = 0; j < 4; ++j) f[i + j] = v4[j];
    }
    bf16x8 s0, s1, g0, g1;
    #pragma unroll
    for (int j = 0; j < 8; ++j) {
        s0[j] = (__bf16)f[j];
        s1[j] = (__bf16)f[8 + j];
        float gq0 = sgnf(bvq[h * HD + c0 + j])     * sgnf(bvk[h * HD + c0 + j]);
        float gq1 = sgnf(bvq[h * HD + c0 + 8 + j]) * sgnf(bvk[h * HD + c0 + 8 + j]);
        g0[j] = (__bf16)(f[j] * gq0);
        g1[j] = (__bf16)(f[8 + j] * gq1);
    }
    *(bf16x8*)(xb + rowbase)     = s0;
    *(bf16x8*)(xb + rowbase + 8) = s1;
    *(bf16x8*)(xq + rowbase)     = g0;
    *(bf16x8*)(xq + rowbase + 8) = g1;
    *(bf16x8*)&tile[r][c0]     = s0;
    *(bf16x8*)&tile[r][c0 + 8] = s1;

    __syncthreads();

    const int d = tid >> 2, t0c = (tid & 3) * 16;
    const float g = sgnf(bvv[h * HD + d]);   // fold sign(bvv) into V source
    __bf16 ov[16];
    #pragma unroll
    for (int i = 0; i < 16; ++i) ov[i] = (__bf16)((float)tile[t0c + i][d] * g);
    bf16x8 o0, o1;
    #pragma unroll
    for (int j = 0; j < 8; ++j) { o0[j] = ov[j]; o1[j] = ov[8 + j]; }
    const size_t obase = ((size_t)((b * NH + h) * HD + d)) * T_LEN + tt * 64 + t0c;
    *(bf16x8*)(xt + obase)     = o0;
    *(bf16x8*)(xt + obase + 8) = o1;
}

// ---------------- main: split schedule + lean body (literal ring indices, ptr staging, zero-VALU Q) ----------------
// Pipeline = r8-proven: K 3-ring + V 2-ring, counted vmcnt(2)/vmcnt(0)
// self-sufficient waits, pinned issue order V(t+1) then K(t+2).
__global__ __launch_bounds__(256, 4) void mba_main(
    const __bf16* __restrict__ xq, const __bf16* __restrict__ xb,
    const __bf16* __restrict__ xt,
    float* __restrict__ out, float* __restrict__ ws2, int tbase)
{
    __shared__ __align__(16) __bf16 Kb[3][64][64];   // 24 KB
    __shared__ __align__(16) __bf16 Vb[2][64][64];   // 16 KB

    const int bid = blockIdx.x;
    const u32 tk = TASKS[tbase + (bid >> 5)];
    const int qt  = tk & 63;
    const int lo  = (tk >> 6) & 63;
    const int CL  = (tk >> 12) & 63;
    const int dst = tk >> 18;

    const int bh = bid & 31;                 // low bits -> XCD locality on (b,h)
    const int b = bh >> 4, h = bh & 15;
    const int q0 = qt * 64;

    const int tid = threadIdx.x;
    const int w = tid >> 6, l = tid & 63;
    const int c = l & 31, hi = l >> 5;
    const int qh = w & 1, sh = w >> 1;

    const size_t xb_bh = (size_t)b * T_LEN * DIM + h * HD;      // row stride DIM
    const size_t xt_bh = (size_t)((b * NH + h) * HD) * T_LEN;   // row stride T_LEN

    // staging: lane covers (row = r0 + l>>3, granule = l&7); source granule
    // pre-swizzled by row&7 (involution; fragment reads apply the same XOR)
    const int rr = l >> 3;
    const int sw = ((l & 7) ^ rr) << 3;

    // lane-fixed staging source pointers (start at tile lo); constant strides
    const __bf16* kst = xb + xb_bh + (size_t)(lo * 64 + w * 8 + rr) * DIM + sw;
    const __bf16* vst = xt + xt_bh + (size_t)(w * 8 + rr) * T_LEN + lo * 64 + sw;
    const size_t KROW32 = (size_t)32 * DIM;
    const size_t VROW32 = (size_t)32 * T_LEN;
    const size_t KTILE  = (size_t)64 * DIM;

    // prologue staging, order pinned for the vmcnt invariant: K0, V0, K1
    gload16(kst,          &Kb[0][w * 8][0]);
    gload16(kst + KROW32, &Kb[0][w * 8 + 32][0]);
    gload16(vst,          &Vb[0][w * 8][0]);
    gload16(vst + VROW32, &Vb[0][w * 8 + 32][0]);
    if (CL >= 2) {
        gload16(kst + KTILE,          &Kb[1][w * 8][0]);
        gload16(kst + KTILE + KROW32, &Kb[1][w * 8 + 32][0]);
    }
    kst += 2 * KTILE;   // next K stage: tile lo+2
    vst += 64;          // next V stage: tile lo+1

    // ---- Q fragments: pure 16B loads from pre-gated xq (zero VALU) ----
    bf16x8 qa[4];
    {
        const __bf16* qp = xq + xb_bh + (size_t)(q0 + qh * 32 + c) * DIM + hi * 8;
        #pragma unroll
        for (int m = 0; m < 4; ++m)
            qa[m] = *(const bf16x8*)(qp + m * 16);
    }

    f32x16 o[2];
    #pragma unroll
    for (int nd = 0; nd < 2; ++nd)
        #pragma unroll
        for (int i = 0; i < 16; ++i) o[nd][i] = 0.f;

    const int krow = sh * 32 + c;      // A-operand row for S^T (s index)
    const int swz = (c & 7) << 4;      // fragment-read deswizzle (row&7 == c&7)

    // body with COMPILE-TIME ring indices KB (mod 3) and VB (mod 2)
    auto body = [&](int lt, auto kbT, auto vbT) {
        constexpr int KB = decltype(kbT)::v;
        constexpr int VB = decltype(vbT)::v;
        const bool last = (lt == CL - 1);
        const bool diag = (lo + lt == qt);
        // SELF-SUFFICIENT wait: at body top only K_{lt+1}x2 may stay in flight.
        if (last) { asm volatile("s_waitcnt vmcnt(0)" ::: "memory"); }
        else      { asm volatile("s_waitcnt vmcnt(2)" ::: "memory"); }
        __builtin_amdgcn_sched_barrier(0);
        __builtin_amdgcn_s_barrier();
        __builtin_amdgcn_sched_barrier(0);

        // ---- prefetch: V(lt+1) FIRST, then K(lt+2); order pinned ----
        if (lt + 1 < CL) {
            gload16(vst,          &Vb[VB ^ 1][w * 8][0]);
            gload16(vst + VROW32, &Vb[VB ^ 1][w * 8 + 32][0]);
            vst += 64;
        }
        __builtin_amdgcn_sched_barrier(0);
        if (lt + 2 < CL) {
            gload16(kst,          &Kb[(KB + 2) % 3][w * 8][0]);
            gload16(kst + KROW32, &Kb[(KB + 2) % 3][w * 8 + 32][0]);
            kst += KTILE;
        }
        __builtin_amdgcn_sched_barrier(0);

        // ---- S^T = K Q^T : D[s=(r&3)+8(r>>2)+4hi (+32sh)][q = qh*32+c] ----
        f32x16 ss;
        #pragma unroll
        for (int i = 0; i < 16; ++i) ss[i] = 0.f;
        #pragma unroll
        for (int m = 0; m < 4; ++m) {
            bf16x8 kf = *(const bf16x8*)((const char*)&Kb[KB][krow][0]
                          + ((m * 32 + hi * 16) ^ swz));
            ss = __builtin_amdgcn_mfma_f32_32x32x16_bf16(kf, qa[m], ss, 0, 0, 0);
        }

        // ---- sigmoid(0.5*s): pk mul/add + scalar exp2/rcp + cvt_pk pack ----
        u32 W[8];
        #pragma unroll
        for (int i = 0; i < 8; ++i) {
            const int r0 = 2 * i;
            f32x2 z; z.x = ss[r0]; z.y = ss[r0 + 1];
            z = z * (-0.72134752f);                 // v_pk_mul_f32
            f32x2 e;
            e.x = __builtin_amdgcn_exp2f(z.x);
            e.y = __builtin_amdgcn_exp2f(z.y);
            e = e + 1.0f;                           // v_pk_add_f32
            float p0 = __builtin_amdgcn_rcpf(e.x);
            float p1 = __builtin_amdgcn_rcpf(e.y);
            if (diag) {                             // causal mask, diagonal tile
                const int sl = (r0 & 3) + 8 * (r0 >> 2) + 4 * hi;
                const int sg = sh * 32 + sl;
                const int qg = qh * 32 + c;
                if (sg > qg)     p0 = 0.f;
                if (sg + 1 > qg) p1 = 0.f;
            }
            asm("v_cvt_pk_bf16_f32 %0, %1, %2" : "=v"(W[i]) : "v"(p0), "v"(p1));
        }

        // ---- in-register transpose: 4x permlane32_swap assembles A-fragments ----
        asm volatile("v_permlane32_swap_b32 %0, %1" : "+v"(W[0]), "+v"(W[2]));
        asm volatile("v_permlane32_swap_b32 %0, %1" : "+v"(W[1]), "+v"(W[3]));
        asm volatile("v_permlane32_swap_b32 %0, %1" : "+v"(W[4]), "+v"(W[6]));
        asm volatile("v_permlane32_swap_b32 %0, %1" : "+v"(W[5]), "+v"(W[7]));
        bf16x8 pa0 = __builtin_bit_cast(bf16x8, (u32x4){W[0], W[1], W[2], W[3]});
        bf16x8 pa1 = __builtin_bit_cast(bf16x8, (u32x4){W[4], W[5], W[6], W[7]});

        // ---- O += P V : A=P (row=q, k=s), B=V rows of Vb (col=d, k=s) ----
        // V's s-dim is the COLUMN of Vb[d][s]: the wave's s-half offset sh*64
        // bytes lives in the column offset (K carries sh in its ROW instead).
        #pragma unroll
        for (int m = 0; m < 2; ++m) {
            const bf16x8 paM = m ? pa1 : pa0;       // static after unroll
            #pragma unroll
            for (int nd = 0; nd < 2; ++nd) {
                bf16x8 vf = *(const bf16x8*)((const char*)&Vb[VB][nd * 32 + c][0]
                              + ((sh * 64 + m * 32 + hi * 16) ^ swz));
                o[nd] = __builtin_amdgcn_mfma_f32_32x32x16_bf16(paM, vf, o[nd], 0, 0, 0);
            }
        }
    };

    // kv loop unrolled by 6 = lcm(3,2): ring indices are literals per slot
    for (int t = 0; t < CL; t += 6) {
        body(t, ICT<0>{}, ICT<0>{});
        if (t + 1 < CL) body(t + 1, ICT<1>{}, ICT<1>{});
        if (t + 2 < CL) body(t + 2, ICT<2>{}, ICT<0>{});
        if (t + 3 < CL) body(t + 3, ICT<0>{}, ICT<1>{});
        if (t + 4 < CL) body(t + 4, ICT<1>{}, ICT<0>{});
        if (t + 5 < CL) body(t + 5, ICT<2>{}, ICT<1>{});
    }

    // ---- epilogue: reduce s-halves through LDS scratch, then store ----
    __syncthreads();                               // all ring reads/DMA done
    float (*osc)[64] = (float(*)[64]) & Kb[0][0][0];   // 16 KB scratch

    if (sh == 1) {
        #pragma unroll
        for (int r = 0; r < 16; ++r) {
            const int qloc = (r & 3) + 8 * (r >> 2) + 4 * hi;
            osc[qh * 32 + qloc][c]      = o[0][r];
            osc[qh * 32 + qloc][32 + c] = o[1][r];
        }
    }
    __syncthreads();
    if (sh == 0) {
        if (dst == 0) {
            #pragma unroll
            for (int r = 0; r < 16; ++r) {
                const int qloc = (r & 3) + 8 * (r >> 2) + 4 * hi;
                const size_t row = (size_t)(b * T_LEN + q0 + qh * 32 + qloc) * DIM + h * HD;
                out[row + c]      = o[0][r] + osc[qh * 32 + qloc][c];
                out[row + 32 + c] = o[1][r] + osc[qh * 32 + qloc][32 + c];
            }
        } else {
            // partial tile: ws2[((qt-16)*32 + bh)*2 + (dst-1)][q][d]
            float* wp = ws2 + (size_t)((((qt - 16) * 32 + bh) * 2) + (dst - 1)) * 4096;
            #pragma unroll
            for (int r = 0; r < 16; ++r) {
                const int qloc = (r & 3) + 8 * (r >> 2) + 4 * hi;
                const int qrow = qh * 32 + qloc;
                wp[qrow * 64 + c]      = o[0][r] + osc[qrow][c];
                wp[qrow * 64 + 32 + c] = o[1][r] + osc[qrow][32 + c];
            }
        }
    }
}

// ---------------- reduce: out[tile] = wsA + wsB for the 512 split tiles ----------------
__global__ __launch_bounds__(256) void reduce_kernel(
    const float* __restrict__ ws2, float* __restrict__ out)
{
    const int bid = blockIdx.x;          // 2048 = 512 tiles x 4 quarters
    const int tile = bid >> 2, q4 = bid & 3;
    const int qtw = tile >> 5, bh = tile & 31;   // qt = 16 + qtw
    const int b = bh >> 4, h = bh & 15;

    const float* pa = ws2 + (size_t)((qtw * 32 + bh) * 2) * 4096;
    const float* pb = pa + 4096;

    const int e = q4 * 1024 + threadIdx.x * 4;
    const int qr = e >> 6, d = e & 63;

    f32x4 va = *(const f32x4*)(pa + e);
    f32x4 vb = *(const f32x4*)(pb + e);
    f32x4 s = va + vb;
    *(f32x4*)(out + (size_t)(b * T_LEN + (16 + qtw) * 64 + qr) * DIM + h * HD + d) = s;
}

// ---------------- fallback (round-1 kernel) if ws too small ----------------
__global__ __launch_bounds__(256) void mba_fallback(
    const float* __restrict__ x,
    const float* __restrict__ bvq,
    const float* __restrict__ bvk,
    const float* __restrict__ bvv,
    float* __restrict__ out)
{
    __shared__ __align__(16) __bf16 Kb[64][72];
    __shared__ __align__(16) __bf16 Vt[HD][72];
    __shared__ __align__(16) __bf16 Pb[4][16][72];

    const int bid = blockIdx.x;
    const int qt  = (NQT - 1) - (bid & (NQT - 1));
    const int bh  = bid >> 5;
    const int b   = bh >> 4;
    const int h   = bh & 15;

    const int tid = threadIdx.x;
    const int w   = tid >> 6;
    const int l   = tid & 63;
    const int lq  = l & 15;
    const int lh  = l >> 4;

    const int  q0    = qt * 64;
    const long xbase = ((long)b * T_LEN) * DIM + h * HD;

    bf16x8 qa[2];
    {
        const int   qrow = q0 + w * 16 + lq;
        const float* qp  = x + xbase + (long)qrow * DIM + lh * 8;
        const float* gp  = bvq + h * HD + lh * 8;
        #pragma unroll
        for (int ks = 0; ks < 2; ++ks)
            #pragma unroll
            for (int j = 0; j < 8; ++j)
                qa[ks][j] = (__bf16)(qp[ks * 32 + j] * sgnf(gp[ks * 32 + j]));
    }

    f32x4 o[4];
    #pragma unroll
    for (int n = 0; n < 4; ++n) o[n] = (f32x4){0.f, 0.f, 0.f, 0.f};

    const int r_st = tid >> 2;
    const int c0   = (tid & 3) * 16;
    const float* gk = bvk + h * HD + c0;
    const float* gv = bvv + h * HD + c0;

    for (int kvt = 0; kvt <= qt; ++kvt) {
        const int kv0 = kvt * 64;
        __syncthreads();
        {
            const float* kp = x + xbase + (long)(kv0 + r_st) * DIM + c0;
            __bf16 kb[16];
            #pragma unroll
            for (int i = 0; i < 16; ++i) kb[i] = (__bf16)(kp[i] * sgnf(gk[i]));
            *(bf16x8*)&Kb[r_st][c0]     = *(bf16x8*)&kb[0];
            *(bf16x8*)&Kb[r_st][c0 + 8] = *(bf16x8*)&kb[8];
            #pragma unroll
            for (int i = 0; i < 16; ++i)
                Vt[c0 + i][r_st] = (__bf16)(kp[i] * sgnf(gv[i]));
        }
        __syncthreads();

        f32x4 s[4];
        #pragma unroll
        for (int n = 0; n < 4; ++n) s[n] = (f32x4){0.f, 0.f, 0.f, 0.f};
        #pragma unroll
        for (int ks = 0; ks < 2; ++ks)
            #pragma unroll
            for (int n = 0; n < 4; ++n) {
                bf16x8 kf = *(const bf16x8*)&Kb[n * 16 + lq][ks * 32 + lh * 8];
                s[n] = __builtin_amdgcn_mfma_f32_16x16x32_bf16(qa[ks], kf, s[n], 0, 0, 0);
            }

        const bool diag = (kvt == qt);
        #pragma unroll
        for (int n = 0; n < 4; ++n)
            #pragma unroll
            for (int j = 0; j < 4; ++j) {
                float sc = s[n][j];
                float p = __builtin_amdgcn_rcpf(
                              1.f + __builtin_amdgcn_exp2f(-0.72134752f * sc));
                if (diag && (n * 16 + lq) > (w * 16 + lh * 4 + j)) p = 0.f;
                Pb[w][lh * 4 + j][n * 16 + lq] = (__bf16)p;
            }

        #pragma unroll
        for (int ks = 0; ks < 2; ++ks) {
            bf16x8 pf = *(const bf16x8*)&Pb[w][lq][ks * 32 + lh * 8];
            #pragma unroll
            for (int n = 0; n < 4; ++n) {
                bf16x8 vf = *(const bf16x8*)&Vt[n * 16 + lq][ks * 32 + lh * 8];
                o[n] = __builtin_amdgcn_mfma_f32_16x16x32_bf16(pf, vf, o[n], 0, 0, 0);
            }
        }
    }

    float* op = out + ((long)b * T_LEN + q0 + w * 16) * DIM + h * HD;
    #pragma unroll
    for (int n = 0; n < 4; ++n)
        #pragma unroll
        for (int j = 0; j < 4; ++j)
            op[(long)(lh * 4 + j) * DIM + n * 16 + lq] = o[n][j];
}

extern "C" void kernel_launch(void* const* d_in, const int* in_sizes, int n_in,
                              void* d_out, int out_size, void* d_ws, size_t ws_size,
                              hipStream_t stream) {
    (void)in_sizes; (void)n_in; (void)out_size;
    const float* x   = (const float*)d_in[0];
    const float* bvq = (const float*)d_in[1];
    const float* bvk = (const float*)d_in[2];
    const float* bvv = (const float*)d_in[3];
    float* out = (float*)d_out;

    const size_t XB_BYTES = (size_t)NB * T_LEN * DIM * sizeof(__bf16);  // 8 MB
    const size_t XQ_BYTES = XB_BYTES;                                    // 8 MB
    const size_t XT_BYTES = XB_BYTES;                                    // 8 MB
    const size_t W2_BYTES = (size_t)16 * 32 * 2 * 4096 * sizeof(float);  // 16 MB

    if (ws_size < XB_BYTES + XQ_BYTES + XT_BYTES) {
        mba_fallback<<<NB * NH * NQT, 256, 0, stream>>>(x, bvq, bvk, bvv, out);
        return;
    }

    __bf16* xb = (__bf16*)d_ws;
    __bf16* xq = xb + (size_t)NB * T_LEN * DIM;
    __bf16* xt = xq + (size_t)NB * T_LEN * DIM;

    prep_kernel<<<NB * NQT * NH, 256, 0, stream>>>(x, bvq, bvk, bvv, xb, xq, xt);

    if (ws_size >= XB_BYTES + XQ_BYTES + XT_BYTES + W2_BYTES) {
        float* ws2 = (float*)((char*)d_ws + XB_BYTES + XQ_BYTES + XT_BYTES);
        mba_main<<<NSPLIT * 32, 256, 0, stream>>>(xq, xb, xt, out, ws2, 0);
        reduce_kernel<<<2048, 256, 0, stream>>>(ws2, out);
    } else {
        // mono schedule: 32 direct tasks/bh, no reduce
        mba_main<<<32 * 32, 256, 0, stream>>>(xq, xb, xt, out, nullptr, 48);
    }
}

// Round 16
// 47.898 us; speedup vs baseline: 1.0536x; 1.0536x over previous
//
#include <hip/hip_runtime.h>
#include <hip/hip_bf16.h>
#include <stdint.h>

#define DIM 1024
#define T_LEN 2048
#define NB 2
#define NH 16
#define HD 64
#define NQT 32   // 2048/64 q-tiles

typedef float f32x2 __attribute__((ext_vector_type(2)));
typedef float f32x4 __attribute__((ext_vector_type(4)));
typedef float f32x16 __attribute__((ext_vector_type(16)));
typedef __bf16 bf16x8 __attribute__((ext_vector_type(8)));
typedef __bf16 bf16x2 __attribute__((ext_vector_type(2)));
typedef unsigned int u32;
typedef unsigned int u32x4 __attribute__((ext_vector_type(4)));

template <int N> struct ICT { static constexpr int v = N; };

__device__ __forceinline__ float sgnf(float v) {
    return (v > 0.f) ? 1.f : ((v < 0.f) ? -1.f : 0.f);
}

// async global -> LDS, 16B per lane; LDS dest is wave-uniform base + lane*16
__device__ __forceinline__ void gload16(const __bf16* g, __bf16* l) {
    __builtin_amdgcn_global_load_lds(
        (__attribute__((address_space(1))) void*)g,
        (__attribute__((address_space(3))) void*)l,
        16, 0, 0);
}

// ---------------- prepass: x(f32) -> Xb (bf16), Xq (bf16, QK-SIGN-GATED), Xt (bf16 [b][h][d][t], V-SIGN-GATED) ----------------
__global__ __launch_bounds__(256) void prep_kernel(
    const float* __restrict__ x, const float* __restrict__ bvq,
    const float* __restrict__ bvk, const float* __restrict__ bvv,
    __bf16* __restrict__ xb, __bf16* __restrict__ xq, __bf16* __restrict__ xt)
{
    __shared__ __align__(16) __bf16 tile[64][72];

    const int bid = blockIdx.x;
    const int h = bid & 15, tmp = bid >> 4, tt = tmp & 31, b = tmp >> 5;
    const int tid = threadIdx.x;
    const int r = tid >> 2, c0 = (tid & 3) * 16;

    const size_t rowbase = ((size_t)(b * T_LEN + tt * 64 + r)) * DIM + h * HD + c0;
    const float* xp = x + rowbase;

    float f[16];
    #pragma unroll
    for (int i = 0; i < 16; i += 4) {
        f32x4 v4 = *(const f32x4*)(xp + i);
        #pragma unroll
        for (int j = 0; j < 4; ++j) f[i + j] = v4[j];
    }
    bf16x8 s0, s1, g0, g1;
    #pragma unroll
    for (int j = 0; j < 8; ++j) {
        s0[j] = (__bf16)f[j];
        s1[j] = (__bf16)f[8 + j];
        float gq0 = sgnf(bvq[h * HD + c0 + j])     * sgnf(bvk[h * HD + c0 + j]);
        float gq1 = sgnf(bvq[h * HD + c0 + 8 + j]) * sgnf(bvk[h * HD + c0 + 8 + j]);
        g0[j] = (__bf16)(f[j] * gq0);
        g1[j] = (__bf16)(f[8 + j] * gq1);
    }
    *(bf16x8*)(xb + rowbase)     = s0;
    *(bf16x8*)(xb + rowbase + 8) = s1;
    *(bf16x8*)(xq + rowbase)     = g0;
    *(bf16x8*)(xq + rowbase + 8) = g1;
    *(bf16x8*)&tile[r][c0]     = s0;
    *(bf16x8*)&tile[r][c0 + 8] = s1;

    __syncthreads();

    const int d = tid >> 2, t0c = (tid & 3) * 16;
    const float g = sgnf(bvv[h * HD + d]);   // fold sign(bvv) into V source
    __bf16 ov[16];
    #pragma unroll
    for (int i = 0; i < 16; ++i) ov[i] = (__bf16)((float)tile[t0c + i][d] * g);
    bf16x8 o0, o1;
    #pragma unroll
    for (int j = 0; j < 8; ++j) { o0[j] = ov[j]; o1[j] = ov[8 + j]; }
    const size_t obase = ((size_t)((b * NH + h) * HD + d)) * T_LEN + tt * 64 + t0c;
    *(bf16x8*)(xt + obase)     = o0;
    *(bf16x8*)(xt + obase + 8) = o1;
}

// ---------------- main: r8 mono schedule + lean body + zero-VALU Q + setprio ----------------
// One 64-row q-tile per block, 4 waves: wave w -> (q-half qh=w&1, s-half sh=w>>1).
// Pipeline = r8-proven VERBATIM: K 3-ring + V 2-ring, counted vmcnt(2)/vmcnt(0)
// self-sufficient waits, pinned issue order V(t+1) then K(t+2). Lean body:
// unroll-by-6 literal ring indices, pointer-increment staging, pk-sigmoid +
// v_cvt_pk_bf16_f32, Q from pre-gated xq (pure loads). T5 setprio around MFMA.
__global__ __launch_bounds__(256, 4) void mba_main(
    const __bf16* __restrict__ xq, const __bf16* __restrict__ xb,
    const __bf16* __restrict__ xt, float* __restrict__ out)
{
    __shared__ __align__(16) __bf16 Kb[3][64][64];   // 24 KB
    __shared__ __align__(16) __bf16 Vb[2][64][64];   // 16 KB

    const int bid = blockIdx.x;
    // balanced map: u in 0..31, jj=u>>3, aa=u&7 -> qt = 8jj + (jj odd ? 7-aa : aa)
    // (bijective; every CU's 4 resident blocks sum to exactly 66 bodies)
    const int u = bid >> 5;
    const int jj = u >> 3, aa = u & 7;
    const int qt = 8 * jj + ((jj & 1) ? (7 - aa) : aa);
    const int bh = bid & 31;                 // low bits -> XCD locality on (b,h)
    const int b = bh >> 4, h = bh & 15;
    const int q0 = qt * 64;
    const int CL = qt + 1;

    const int tid = threadIdx.x;
    const int w = tid >> 6, l = tid & 63;
    const int c = l & 31, hi = l >> 5;
    const int qh = w & 1, sh = w >> 1;

    const size_t xb_bh = (size_t)b * T_LEN * DIM + h * HD;      // row stride DIM
    const size_t xt_bh = (size_t)((b * NH + h) * HD) * T_LEN;   // row stride T_LEN

    // staging: lane covers (row = r0 + l>>3, granule = l&7); source granule
    // pre-swizzled by row&7 (involution; fragment reads apply the same XOR)
    const int rr = l >> 3;
    const int sw = ((l & 7) ^ rr) << 3;

    // lane-fixed staging source pointers; constant strides per tile
    const __bf16* kst = xb + xb_bh + (size_t)(w * 8 + rr) * DIM + sw;
    const __bf16* vst = xt + xt_bh + (size_t)(w * 8 + rr) * T_LEN + sw;
    const size_t KROW32 = (size_t)32 * DIM;
    const size_t VROW32 = (size_t)32 * T_LEN;
    const size_t KTILE  = (size_t)64 * DIM;

    // prologue staging, order pinned for the vmcnt invariant: K0, V0, K1
    gload16(kst,          &Kb[0][w * 8][0]);
    gload16(kst + KROW32, &Kb[0][w * 8 + 32][0]);
    gload16(vst,          &Vb[0][w * 8][0]);
    gload16(vst + VROW32, &Vb[0][w * 8 + 32][0]);
    if (CL >= 2) {
        gload16(kst + KTILE,          &Kb[1][w * 8][0]);
        gload16(kst + KTILE + KROW32, &Kb[1][w * 8 + 32][0]);
    }
    kst += 2 * KTILE;   // next K stage: tile 2
    vst += 64;          // next V stage: tile 1

    // ---- Q fragments: pure 16B loads from pre-gated xq (zero VALU) ----
    bf16x8 qa[4];
    {
        const __bf16* qp = xq + xb_bh + (size_t)(q0 + qh * 32 + c) * DIM + hi * 8;
        #pragma unroll
        for (int m = 0; m < 4; ++m)
            qa[m] = *(const bf16x8*)(qp + m * 16);
    }

    f32x16 o[2];
    #pragma unroll
    for (int nd = 0; nd < 2; ++nd)
        #pragma unroll
        for (int i = 0; i < 16; ++i) o[nd][i] = 0.f;

    const int krow = sh * 32 + c;      // A-operand row for S^T (s index)
    const int swz = (c & 7) << 4;      // fragment-read deswizzle (row&7 == c&7)

    // body with COMPILE-TIME ring indices KB (mod 3) and VB (mod 2)
    auto body = [&](int lt, auto kbT, auto vbT) {
        constexpr int KB = decltype(kbT)::v;
        constexpr int VB = decltype(vbT)::v;
        const bool last = (lt == CL - 1);
        // SELF-SUFFICIENT wait: at body top only K_{lt+1}x2 may stay in flight.
        if (last) { asm volatile("s_waitcnt vmcnt(0)" ::: "memory"); }
        else      { asm volatile("s_waitcnt vmcnt(2)" ::: "memory"); }
        __builtin_amdgcn_sched_barrier(0);
        __builtin_amdgcn_s_barrier();
        __builtin_amdgcn_sched_barrier(0);

        // ---- prefetch: V(lt+1) FIRST, then K(lt+2); order pinned ----
        if (lt + 1 < CL) {
            gload16(vst,          &Vb[VB ^ 1][w * 8][0]);
            gload16(vst + VROW32, &Vb[VB ^ 1][w * 8 + 32][0]);
            vst += 64;
        }
        __builtin_amdgcn_sched_barrier(0);
        if (lt + 2 < CL) {
            gload16(kst,          &Kb[(KB + 2) % 3][w * 8][0]);
            gload16(kst + KROW32, &Kb[(KB + 2) % 3][w * 8 + 32][0]);
            kst += KTILE;
        }
        __builtin_amdgcn_sched_barrier(0);

        // ---- S^T = K Q^T : D[s=(r&3)+8(r>>2)+4hi (+32sh)][q = qh*32+c] ----
        f32x16 ss;
        #pragma unroll
        for (int i = 0; i < 16; ++i) ss[i] = 0.f;
        __builtin_amdgcn_s_setprio(1);
        #pragma unroll
        for (int m = 0; m < 4; ++m) {
            bf16x8 kf = *(const bf16x8*)((const char*)&Kb[KB][krow][0]
                          + ((m * 32 + hi * 16) ^ swz));
            ss = __builtin_amdgcn_mfma_f32_32x32x16_bf16(kf, qa[m], ss, 0, 0, 0);
        }
        __builtin_amdgcn_s_setprio(0);

        // ---- sigmoid(0.5*s): pk mul/add + scalar exp2/rcp + cvt_pk pack ----
        u32 W[8];
        #pragma unroll
        for (int i = 0; i < 8; ++i) {
            const int r0 = 2 * i;
            f32x2 z; z.x = ss[r0]; z.y = ss[r0 + 1];
            z = z * (-0.72134752f);                 // v_pk_mul_f32
            f32x2 e;
            e.x = __builtin_amdgcn_exp2f(z.x);
            e.y = __builtin_amdgcn_exp2f(z.y);
            e = e + 1.0f;                           // v_pk_add_f32
            float p0 = __builtin_amdgcn_rcpf(e.x);
            float p1 = __builtin_amdgcn_rcpf(e.y);
            if (last) {                             // causal mask, diagonal tile
                const int sl = (r0 & 3) + 8 * (r0 >> 2) + 4 * hi;
                const int sg = sh * 32 + sl;
                const int qg = qh * 32 + c;
                if (sg > qg)     p0 = 0.f;
                if (sg + 1 > qg) p1 = 0.f;
            }
            asm("v_cvt_pk_bf16_f32 %0, %1, %2" : "=v"(W[i]) : "v"(p0), "v"(p1));
        }

        // ---- in-register transpose: 4x permlane32_swap assembles A-fragments ----
        asm volatile("v_permlane32_swap_b32 %0, %1" : "+v"(W[0]), "+v"(W[2]));
        asm volatile("v_permlane32_swap_b32 %0, %1" : "+v"(W[1]), "+v"(W[3]));
        asm volatile("v_permlane32_swap_b32 %0, %1" : "+v"(W[4]), "+v"(W[6]));
        asm volatile("v_permlane32_swap_b32 %0, %1" : "+v"(W[5]), "+v"(W[7]));
        bf16x8 pa0 = __builtin_bit_cast(bf16x8, (u32x4){W[0], W[1], W[2], W[3]});
        bf16x8 pa1 = __builtin_bit_cast(bf16x8, (u32x4){W[4], W[5], W[6], W[7]});

        // ---- O += P V : A=P (row=q, k=s), B=V rows of Vb (col=d, k=s) ----
        // V's s-dim is the COLUMN of Vb[d][s]: the wave's s-half offset sh*64
        // bytes lives in the column offset (K carries sh in its ROW instead).
        __builtin_amdgcn_s_setprio(1);
        #pragma unroll
        for (int m = 0; m < 2; ++m) {
            const bf16x8 paM = m ? pa1 : pa0;       // static after unroll
            #pragma unroll
            for (int nd = 0; nd < 2; ++nd) {
                bf16x8 vf = *(const bf16x8*)((const char*)&Vb[VB][nd * 32 + c][0]
                              + ((sh * 64 + m * 32 + hi * 16) ^ swz));
                o[nd] = __builtin_amdgcn_mfma_f32_32x32x16_bf16(paM, vf, o[nd], 0, 0, 0);
            }
        }
        __builtin_amdgcn_s_setprio(0);
    };

    // kv loop unrolled by 6 = lcm(3,2): ring indices are literals per slot
    for (int t = 0; t < CL; t += 6) {
        body(t, ICT<0>{}, ICT<0>{});
        if (t + 1 < CL) body(t + 1, ICT<1>{}, ICT<1>{});
        if (t + 2 < CL) body(t + 2, ICT<2>{}, ICT<0>{});
        if (t + 3 < CL) body(t + 3, ICT<0>{}, ICT<1>{});
        if (t + 4 < CL) body(t + 4, ICT<1>{}, ICT<0>{});
        if (t + 5 < CL) body(t + 5, ICT<2>{}, ICT<1>{});
    }

    // ---- epilogue: reduce the two s-halves, store (signs folded in prepass) ----
    __syncthreads();                               // all ring reads/DMA done
    float (*osc)[64] = (float(*)[64]) & Kb[0][0][0];   // 16 KB scratch on K ring

    if (sh == 1) {
        #pragma unroll
        for (int r = 0; r < 16; ++r) {
            const int qloc = (r & 3) + 8 * (r >> 2) + 4 * hi;
            osc[qh * 32 + qloc][c]      = o[0][r];
            osc[qh * 32 + qloc][32 + c] = o[1][r];
        }
    }
    __syncthreads();
    if (sh == 0) {
        #pragma unroll
        for (int r = 0; r < 16; ++r) {
            const int qloc = (r & 3) + 8 * (r >> 2) + 4 * hi;
            const size_t row = (size_t)(b * T_LEN + q0 + qh * 32 + qloc) * DIM + h * HD;
            out[row + c]      = o[0][r] + osc[qh * 32 + qloc][c];
            out[row + 32 + c] = o[1][r] + osc[qh * 32 + qloc][32 + c];
        }
    }
}

// ---------------- fallback (round-1 kernel) if ws too small ----------------
__global__ __launch_bounds__(256) void mba_fallback(
    const float* __restrict__ x,
    const float* __restrict__ bvq,
    const float* __restrict__ bvk,
    const float* __restrict__ bvv,
    float* __restrict__ out)
{
    __shared__ __align__(16) __bf16 Kb[64][72];
    __shared__ __align__(16) __bf16 Vt[HD][72];
    __shared__ __align__(16) __bf16 Pb[4][16][72];

    const int bid = blockIdx.x;
    const int qt  = (NQT - 1) - (bid & (NQT - 1));
    const int bh  = bid >> 5;
    const int b   = bh >> 4;
    const int h   = bh & 15;

    const int tid = threadIdx.x;
    const int w   = tid >> 6;
    const int l   = tid & 63;
    const int lq  = l & 15;
    const int lh  = l >> 4;

    const int  q0    = qt * 64;
    const long xbase = ((long)b * T_LEN) * DIM + h * HD;

    bf16x8 qa[2];
    {
        const int   qrow = q0 + w * 16 + lq;
        const float* qp  = x + xbase + (long)qrow * DIM + lh * 8;
        const float* gp  = bvq + h * HD + lh * 8;
        #pragma unroll
        for (int ks = 0; ks < 2; ++ks)
            #pragma unroll
            for (int j = 0; j < 8; ++j)
                qa[ks][j] = (__bf16)(qp[ks * 32 + j] * sgnf(gp[ks * 32 + j]));
    }

    f32x4 o[4];
    #pragma unroll
    for (int n = 0; n < 4; ++n) o[n] = (f32x4){0.f, 0.f, 0.f, 0.f};

    const int r_st = tid >> 2;
    const int c0   = (tid & 3) * 16;
    const float* gk = bvk + h * HD + c0;
    const float* gv = bvv + h * HD + c0;

    for (int kvt = 0; kvt <= qt; ++kvt) {
        const int kv0 = kvt * 64;
        __syncthreads();
        {
            const float* kp = x + xbase + (long)(kv0 + r_st) * DIM + c0;
            __bf16 kb[16];
            #pragma unroll
            for (int i = 0; i < 16; ++i) kb[i] = (__bf16)(kp[i] * sgnf(gk[i]));
            *(bf16x8*)&Kb[r_st][c0]     = *(bf16x8*)&kb[0];
            *(bf16x8*)&Kb[r_st][c0 + 8] = *(bf16x8*)&kb[8];
            #pragma unroll
            for (int i = 0; i < 16; ++i)
                Vt[c0 + i][r_st] = (__bf16)(kp[i] * sgnf(gv[i]));
        }
        __syncthreads();

        f32x4 s[4];
        #pragma unroll
        for (int n = 0; n < 4; ++n) s[n] = (f32x4){0.f, 0.f, 0.f, 0.f};
        #pragma unroll
        for (int ks = 0; ks < 2; ++ks)
            #pragma unroll
            for (int n = 0; n < 4; ++n) {
                bf16x8 kf = *(const bf16x8*)&Kb[n * 16 + lq][ks * 32 + lh * 8];
                s[n] = __builtin_amdgcn_mfma_f32_16x16x32_bf16(qa[ks], kf, s[n], 0, 0, 0);
            }

        const bool diag = (kvt == qt);
        #pragma unroll
        for (int n = 0; n < 4; ++n)
            #pragma unroll
            for (int j = 0; j < 4; ++j) {
                float sc = s[n][j];
                float p = __builtin_amdgcn_rcpf(
                              1.f + __builtin_amdgcn_exp2f(-0.72134752f * sc));
                if (diag && (n * 16 + lq) > (w * 16 + lh * 4 + j)) p = 0.f;
                Pb[w][lh * 4 + j][n * 16 + lq] = (__bf16)p;
            }

        #pragma unroll
        for (int ks = 0; ks < 2; ++ks) {
            bf16x8 pf = *(const bf16x8*)&Pb[w][lq][ks * 32 + lh * 8];
            #pragma unroll
            for (int n = 0; n < 4; ++n) {
                bf16x8 vf = *(const bf16x8*)&Vt[n * 16 + lq][ks * 32 + lh * 8];
                o[n] = __builtin_amdgcn_mfma_f32_16x16x32_bf16(pf, vf, o[n], 0, 0, 0);
            }
        }
    }

    float* op = out + ((long)b * T_LEN + q0 + w * 16) * DIM + h * HD;
    #pragma unroll
    for (int n = 0; n < 4; ++n)
        #pragma unroll
        for (int j = 0; j < 4; ++j)
            op[(long)(lh * 4 + j) * DIM + n * 16 + lq] = o[n][j];
}

extern "C" void kernel_launch(void* const* d_in, const int* in_sizes, int n_in,
                              void* d_out, int out_size, void* d_ws, size_t ws_size,
                              hipStream_t stream) {
    (void)in_sizes; (void)n_in; (void)out_size;
    const float* x   = (const float*)d_in[0];
    const float* bvq = (const float*)d_in[1];
    const float* bvk = (const float*)d_in[2];
    const float* bvv = (const float*)d_in[3];
    float* out = (float*)d_out;

    const size_t XB_BYTES = (size_t)NB * T_LEN * DIM * sizeof(__bf16);  // 8 MB
    const size_t XQ_BYTES = XB_BYTES;                                    // 8 MB
    const size_t XT_BYTES = XB_BYTES;                                    // 8 MB

    if (ws_size < XB_BYTES + XQ_BYTES + XT_BYTES) {
        mba_fallback<<<NB * NH * NQT, 256, 0, stream>>>(x, bvq, bvk, bvv, out);
        return;
    }

    __bf16* xb = (__bf16*)d_ws;
    __bf16* xq = xb + (size_t)NB * T_LEN * DIM;
    __bf16* xt = xq + (size_t)NB * T_LEN * DIM;

    prep_kernel<<<NB * NQT * NH, 256, 0, stream>>>(x, bvq, bvk, bvv, xb, xq, xt);
    mba_main<<<NB * NH * NQT, 256, 0, stream>>>(xq, xb, xt, out);
}